// Round 5
// baseline (90.826 us; speedup 1.0000x reference)
//
#include <hip/hip_runtime.h>
#include <hip/hip_bf16.h>
#include <cstddef>

#define NE 65536
#define ND 256
#define NP 8
#define CAP 16384            // per-expert perm capacity
#define TMAX 256             // CAP/64 tiles per expert
#define RBLK 64              // routing blocks
#define EPB (NE / RBLK)      // 1024 edges per routing block

typedef short bf16x8 __attribute__((ext_vector_type(8)));
typedef float f32x4  __attribute__((ext_vector_type(4)));

__device__ __forceinline__ unsigned short f2bf(float f) {
  unsigned int u = __float_as_uint(f);
  u += 0x7FFFu + ((u >> 16) & 1u);   // round-to-nearest-even
  return (unsigned short)(u >> 16);
}

// Per-block idx-dtype sniff: sample 256 odd 32-bit words from the first NE
// words. int64 buffer (values < 8) => all odd words 0. int32 => random idx
// values; P(256 samples all zero) = (1/8)^256 ~ 0.
__device__ __forceinline__ int sniff_is32(const void* idxraw, int* lflag) {
  int tid = threadIdx.x;
  if (tid == 0) *lflag = 0;
  __syncthreads();
  const unsigned int* w = (const unsigned int*)idxraw;
  unsigned int val = w[(blockIdx.x * 256 + tid) * 2 + 1];
  if (__any(val != 0) && (tid & 63) == 0) atomicOr(lflag, 1);
  __syncthreads();
  return *lflag;
}

__device__ __forceinline__ int load_idx(const void* idxraw, int is32, int e) {
  return is32 ? ((const int*)idxraw)[e] : (int)((const long long*)idxraw)[e];
}

// ---- phase 1: per-block LDS histogram (no global atomics) ----
__global__ __launch_bounds__(256) void k_hist(const void* __restrict__ idxraw,
                                              int* __restrict__ counts) {
  __shared__ int h[NP];
  __shared__ int lflag;
  int tid = threadIdx.x;
  int is32 = sniff_is32(idxraw, &lflag);
  if (tid < NP) h[tid] = 0;
  __syncthreads();
  int base = blockIdx.x * EPB;
#pragma unroll
  for (int i = 0; i < EPB / 256; ++i) {
    int p = load_idx(idxraw, is32, base + tid + i * 256);
    atomicAdd(&h[p], 1);                       // LDS atomic
  }
  __syncthreads();
  if (tid < NP) counts[blockIdx.x * NP + tid] = h[tid];
}

// ---- phase 2: exclusive scan over blocks per expert; totals -> cursor ----
__global__ __launch_bounds__(64) void k_scan(const int* __restrict__ counts,
                                             int* __restrict__ bases,
                                             int* __restrict__ cursor) {
  int q = threadIdx.x;
  if (q < NP) {
    int run = 0;
    for (int b = 0; b < RBLK; ++b) {
      bases[b * NP + q] = run;
      run += counts[b * NP + q];
    }
    cursor[q] = run;
  }
}

// ---- phase 3: scatter with LDS cursors seeded from bases ----
__global__ __launch_bounds__(256) void k_scatter(const void* __restrict__ idxraw,
                                                 const int* __restrict__ bases,
                                                 int* __restrict__ perm) {
  __shared__ int cur[NP];
  __shared__ int lflag;
  int tid = threadIdx.x;
  int is32 = sniff_is32(idxraw, &lflag);
  if (tid < NP) cur[tid] = bases[blockIdx.x * NP + tid];
  __syncthreads();
  int base = blockIdx.x * EPB;
#pragma unroll
  for (int i = 0; i < EPB / 256; ++i) {
    int e = base + tid + i * 256;
    int p = load_idx(idxraw, is32, e);
    int slot = atomicAdd(&cur[p], 1);          // LDS atomic
    perm[p * CAP + slot] = e;
  }
}

// ---- prep: W_bil -> B-frag bf16 layout; v_p = b_lr[p] @ W_bil (fp32) ----
__global__ __launch_bounds__(256) void k_prep(const float* __restrict__ Wbil,
                                              const float* __restrict__ blr,
                                              unsigned short* __restrict__ WbT,
                                              float* __restrict__ v) {
  int b = blockIdx.x, t = threadIdx.x;
  if (b < 32) {
    int s = b * 256 + t;                 // slot 0..8191
    int kt = s >> 10, c = (s >> 6) & 15, l = s & 63;
    int col = c * 16 + (l & 15);
    int k0 = kt * 32 + (l >> 4) * 8;
    union { uint4 u; unsigned short h[8]; } uu;
#pragma unroll
    for (int j = 0; j < 8; ++j)
      uu.h[j] = f2bf(Wbil[(k0 + j) * ND + col]);
    *(uint4*)(WbT + (size_t)s * 8) = uu.u;
  } else {
    int p = b - 32;
    float s = 0.f;
    for (int k = 0; k < ND; ++k)
      s = fmaf(blr[p * ND + k], Wbil[k * ND + t], s);
    v[p * ND + t] = s;
  }
}

// ---- C_p = W_lr[p]^T @ W_bil  (bf16 MFMA), written in B-frag layout ----
__global__ __launch_bounds__(256) void k_cpre(const float* __restrict__ Wlr,
                                              const unsigned short* __restrict__ WbT,
                                              unsigned short* __restrict__ Cst) {
  __shared__ unsigned short aF[2048 * 8];      // 32 KiB
  int blk = blockIdx.x;
  int p = blk >> 2;
  int i0 = (blk & 3) * 64;
  int tid = threadIdx.x;
  const float* Wp = Wlr + (size_t)p * ND * ND;
#pragma unroll
  for (int it = 0; it < 8; ++it) {
    int s = tid + it * 256;                    // slot = ((kt*4 + r)*64 + l)
    int kt = s >> 8, r = (s >> 6) & 3, l = s & 63;
    int i = r * 16 + (l & 15);
    int k0 = kt * 32 + (l >> 4) * 8;
    union { uint4 u; unsigned short h[8]; } uu;
#pragma unroll
    for (int j = 0; j < 8; ++j)                // A[i][k] = Wlr[p][k][i0+i]
      uu.h[j] = f2bf(Wp[(size_t)(k0 + j) * ND + i0 + i]);
    *(uint4*)(aF + (size_t)s * 8) = uu.u;
  }
  __syncthreads();
  int w = tid >> 6, l = tid & 63;
  f32x4 zero = {0.f, 0.f, 0.f, 0.f};
  f32x4 acc[16];
#pragma unroll
  for (int c = 0; c < 16; ++c) acc[c] = zero;
  for (int kt = 0; kt < 8; ++kt) {
    bf16x8 a = *(const bf16x8*)(aF + (size_t)((kt * 4 + w) * 64 + l) * 8);
#pragma unroll
    for (int c = 0; c < 16; ++c) {
      bf16x8 bb = *(const bf16x8*)(WbT + (size_t)((kt * 16 + c) * 64 + l) * 8);
      acc[c] = __builtin_amdgcn_mfma_f32_16x16x32_bf16(a, bb, acc[c], 0, 0, 0);
    }
  }
  unsigned short* Cp = Cst + (size_t)p * ND * ND;
#pragma unroll
  for (int c = 0; c < 16; ++c) {
#pragma unroll
    for (int q = 0; q < 4; ++q) {
      int i = i0 + w * 16 + ((l >> 4) * 4) + q;
      int j = c * 16 + (l & 15);
      int pos = ((i >> 5) * 16 + (j >> 4)) * 512 + (((i >> 3) & 3) * 16 + (j & 15)) * 8 + (i & 7);
      Cp[pos] = f2bf(acc[c][q]);
    }
  }
}

// ---- main: per 64-row tile: t = z_src@C_p ; score = (t+v_p)·z_dst + b ----
// v3: ALL 32 B-fragments (this wave's Cst slice, 512B/lane) are prefetched
// into registers at block entry, before/concurrent with the staging gather —
// removes the 32x ~400cy serial L2-load chain that capped R4 at 70us.
// launch_bounds(256,1): LDS (67KB) caps us at 2 blocks/CU anyway, so let
// VGPR grow to hold bfr[4][8] (128 VGPRs).
__global__ __launch_bounds__(256, 1) void k_main(const float* __restrict__ zsrc,
                                                 const float* __restrict__ zdst,
                                                 const int* __restrict__ perm,
                                                 const int* __restrict__ cursor,
                                                 const unsigned short* __restrict__ Cst,
                                                 const float* __restrict__ v,
                                                 const float* __restrict__ bbil,
                                                 float* __restrict__ out) {
  int p = blockIdx.x >> 8;                     // TMAX = 256
  int t = blockIdx.x & 255;
  int cnt = cursor[p];
  if (t * 64 >= cnt) return;
  __shared__ unsigned short aF[2048 * 8];      // 32 KiB A-frag tile
  __shared__ unsigned short zL[64 * 256];      // 32 KiB zdst tile (bf16, swizzled)
  __shared__ int eids[64];
  __shared__ float red[4][64];
  int tid = threadIdx.x;
  int w = tid >> 6, l = tid & 63;
  const unsigned short* Cp = Cst + (size_t)p * ND * ND;

  // ---- B prefetch: issue all 32 independent loads first (L2/L3-resident) ----
  bf16x8 bfr[4][8];
#pragma unroll
  for (int cl = 0; cl < 4; ++cl)
#pragma unroll
    for (int kt = 0; kt < 8; ++kt)
      bfr[cl][kt] = *(const bf16x8*)(Cp + (size_t)((kt * 16 + (w * 4 + cl)) * 64 + l) * 8);

  if (tid < 64) {
    int r = t * 64 + tid;
    eids[tid] = perm[p * CAP + (r < cnt ? r : cnt - 1)];
  }
  __syncthreads();
#pragma unroll
  for (int it = 0; it < 8; ++it) {
    int s = tid + it * 256;
    int kt = s >> 8, rr = (s >> 6) & 3, ll = s & 63;
    int row = rr * 16 + (ll & 15);
    int k0 = kt * 32 + (ll >> 4) * 8;
    const float* src = zsrc + (size_t)eids[row] * ND + k0;
    const float* dsr = zdst + (size_t)eids[row] * ND + k0;
    float f[8], g[8];
    *(float4*)(f)     = *(const float4*)(src);
    *(float4*)(f + 4) = *(const float4*)(src + 4);
    *(float4*)(g)     = *(const float4*)(dsr);
    *(float4*)(g + 4) = *(const float4*)(dsr + 4);
    union { uint4 u; unsigned short h[8]; } ua, ud;
#pragma unroll
    for (int j = 0; j < 8; ++j) { ua.h[j] = f2bf(f[j]); ud.h[j] = f2bf(g[j]); }
    *(uint4*)(aF + (size_t)s * 8) = ua.u;
    unsigned int zb = (unsigned int)(row * 512 + k0 * 2) ^ (unsigned int)((row & 7) << 4);
    *(uint4*)((char*)zL + zb) = ud.u;
  }
  __syncthreads();

  f32x4 zero = {0.f, 0.f, 0.f, 0.f};
  f32x4 acc[4][4];
#pragma unroll
  for (int r = 0; r < 4; ++r)
#pragma unroll
    for (int c = 0; c < 4; ++c) acc[r][c] = zero;
#pragma unroll
  for (int kt = 0; kt < 8; ++kt) {
    bf16x8 a[4];
#pragma unroll
    for (int r = 0; r < 4; ++r)
      a[r] = *(const bf16x8*)(aF + (size_t)((kt * 4 + r) * 64 + l) * 8);
#pragma unroll
    for (int cl = 0; cl < 4; ++cl) {
#pragma unroll
      for (int r = 0; r < 4; ++r)
        acc[r][cl] = __builtin_amdgcn_mfma_f32_16x16x32_bf16(a[r], bfr[cl][kt], acc[r][cl], 0, 0, 0);
    }
  }
  float vloc[4];
#pragma unroll
  for (int cl = 0; cl < 4; ++cl)
    vloc[cl] = v[p * ND + (w * 4 + cl) * 16 + (l & 15)];
#pragma unroll
  for (int r = 0; r < 4; ++r) {
#pragma unroll
    for (int q = 0; q < 4; ++q) {
      int row = r * 16 + ((l >> 4) * 4) + q;   // D-layout: col=l&15, row=(l>>4)*4+reg
      unsigned int swz = (unsigned int)((row & 7) << 4);
      float sv = 0.f;
#pragma unroll
      for (int cl = 0; cl < 4; ++cl) {
        int col = (w * 4 + cl) * 16 + (l & 15);
        unsigned int zb = (unsigned int)(row * 512 + col * 2) ^ swz;
        unsigned short hz = *(const unsigned short*)((const char*)zL + zb);
        float zv = __uint_as_float(((unsigned int)hz) << 16);
        sv = fmaf(acc[r][cl][q] + vloc[cl], zv, sv);
      }
      sv += __shfl_xor(sv, 1, 64);
      sv += __shfl_xor(sv, 2, 64);
      sv += __shfl_xor(sv, 4, 64);
      sv += __shfl_xor(sv, 8, 64);
      if ((l & 15) == 0) red[w][row] = sv;
    }
  }
  __syncthreads();
  if (tid < 64) {
    int gr = t * 64 + tid;
    if (gr < cnt) {
      float sc = red[0][tid] + red[1][tid] + red[2][tid] + red[3][tid] + bbil[0];
      out[eids[tid]] = sc;
    }
  }
}

extern "C" void kernel_launch(void* const* d_in, const int* in_sizes, int n_in,
                              void* d_out, int out_size, void* d_ws, size_t ws_size,
                              hipStream_t stream) {
  // setup_inputs() dict order: z_src, z_dst, W_lr, b_lr, W_bil, b_bil, lr_pair_idx
  const float* zsrc = (const float*)d_in[0];
  const float* zdst = (const float*)d_in[1];
  const float* Wlr  = (const float*)d_in[2];
  const float* blr  = (const float*)d_in[3];
  const float* Wbil = (const float*)d_in[4];
  const float* bbil = (const float*)d_in[5];
  const void*  idx  = (const void*)d_in[6];   // int32 or int64 — sniffed per block
  float* out = (float*)d_out;

  char* ws = (char*)d_ws;
  int* cursor = (int*)ws;                                  // 32 B
  int* counts = (int*)(ws + 4096);                         // 2 KiB
  int* bases  = (int*)(ws + 8192);                         // 2 KiB
  int* perm   = (int*)(ws + 16384);                        // 512 KiB
  unsigned short* WbT = (unsigned short*)(ws + 16384 + (size_t)NP * CAP * 4);            // 128 KiB
  float* v = (float*)(ws + 16384 + (size_t)NP * CAP * 4 + 131072);                       // 8 KiB
  unsigned short* Cst = (unsigned short*)(ws + 16384 + (size_t)NP * CAP * 4 + 131072 + 8192); // 1 MiB

  k_prep<<<40, 256, 0, stream>>>(Wbil, blr, WbT, v);
  k_hist<<<RBLK, 256, 0, stream>>>(idx, counts);
  k_scan<<<1, 64, 0, stream>>>(counts, bases, cursor);
  k_scatter<<<RBLK, 256, 0, stream>>>(idx, bases, perm);
  k_cpre<<<32, 256, 0, stream>>>(Wlr, WbT, Cst);
  k_main<<<NP * TMAX, 256, 0, stream>>>(zsrc, zdst, perm, cursor, Cst, v, bbil, out);
}

// Round 6
// 88.958 us; speedup vs baseline: 1.0210x; 1.0210x over previous
//
#include <hip/hip_runtime.h>
#include <hip/hip_bf16.h>
#include <cstddef>

#define NE 65536
#define ND 256
#define NP 8
#define RBLK 64              // routing blocks
#define EPB (NE / RBLK)      // 1024 edges per routing block

typedef short bf16x8 __attribute__((ext_vector_type(8)));
typedef float f32x4  __attribute__((ext_vector_type(4)));

__device__ __forceinline__ unsigned short f2bf(float f) {
  unsigned int u = __float_as_uint(f);
  u += 0x7FFFu + ((u >> 16) & 1u);   // round-to-nearest-even
  return (unsigned short)(u >> 16);
}

// Per-block idx-dtype sniff: sample 256 odd 32-bit words from the first NE
// words. int64 buffer (values < 8) => all odd words 0. int32 => random idx
// values; P(256 samples all zero) = (1/8)^256 ~ 0.
__device__ __forceinline__ int sniff_is32(const void* idxraw, int* lflag) {
  int tid = threadIdx.x;
  if (tid == 0) *lflag = 0;
  __syncthreads();
  const unsigned int* w = (const unsigned int*)idxraw;
  unsigned int val = w[(blockIdx.x * 256 + tid) * 2 + 1];
  if (__any(val != 0) && (tid & 63) == 0) atomicOr(lflag, 1);
  __syncthreads();
  return *lflag;
}

__device__ __forceinline__ int load_idx(const void* idxraw, int is32, int e) {
  return is32 ? ((const int*)idxraw)[e] : (int)((const long long*)idxraw)[e];
}

// ---- phase 1: per-block LDS histogram ----
__global__ __launch_bounds__(256) void k_hist(const void* __restrict__ idxraw,
                                              int* __restrict__ counts) {
  __shared__ int h[NP];
  __shared__ int lflag;
  int tid = threadIdx.x;
  int is32 = sniff_is32(idxraw, &lflag);
  if (tid < NP) h[tid] = 0;
  __syncthreads();
  int base = blockIdx.x * EPB;
#pragma unroll
  for (int i = 0; i < EPB / 256; ++i) {
    int p = load_idx(idxraw, is32, base + tid + i * 256);
    atomicAdd(&h[p], 1);                       // LDS atomic
  }
  __syncthreads();
  if (tid < NP) counts[blockIdx.x * NP + tid] = h[tid];
}

// ---- phase 2: totals, CSR offsets (off), tile prefix (tb), per-block bases
// hdr[0..8] = off[9] (edge prefix per expert), hdr[9..17] = tb[9] (tile prefix)
__global__ __launch_bounds__(64) void k_scan(const int* __restrict__ counts,
                                             int* __restrict__ hdr,
                                             int* __restrict__ bases) {
  __shared__ int cnt[NP];
  __shared__ int off[NP + 1];
  int q = threadIdx.x;
  if (q < NP) {
    int s = 0;
    for (int b = 0; b < RBLK; ++b) s += counts[b * NP + q];
    cnt[q] = s;
  }
  __syncthreads();
  if (q == 0) {
    int o = 0, tt = 0;
    for (int p = 0; p < NP; ++p) {
      off[p] = o;
      hdr[p] = o;
      hdr[9 + p] = tt;
      o += cnt[p];
      tt += (cnt[p] + 63) >> 6;
    }
    off[NP] = o;
    hdr[NP] = o;
    hdr[9 + NP] = tt;
  }
  __syncthreads();
  if (q < NP) {
    int run = off[q];
    for (int b = 0; b < RBLK; ++b) {
      bases[b * NP + q] = run;
      run += counts[b * NP + q];
    }
  }
}

// ---- phase 3: scatter (CSR perm, LDS cursors) ----
__global__ __launch_bounds__(256) void k_scatter(const void* __restrict__ idxraw,
                                                 const int* __restrict__ bases,
                                                 int* __restrict__ perm) {
  __shared__ int cur[NP];
  __shared__ int lflag;
  int tid = threadIdx.x;
  int is32 = sniff_is32(idxraw, &lflag);
  if (tid < NP) cur[tid] = bases[blockIdx.x * NP + tid];
  __syncthreads();
  int base = blockIdx.x * EPB;
#pragma unroll
  for (int i = 0; i < EPB / 256; ++i) {
    int e = base + tid + i * 256;
    int p = load_idx(idxraw, is32, e);
    int slot = atomicAdd(&cur[p], 1);          // LDS atomic
    perm[slot] = e;
  }
}

// ---- prep: W_bil -> B-frag bf16 layout; v_p = b_lr[p] @ W_bil (fp32) ----
__global__ __launch_bounds__(256) void k_prep(const float* __restrict__ Wbil,
                                              const float* __restrict__ blr,
                                              unsigned short* __restrict__ WbT,
                                              float* __restrict__ v) {
  int b = blockIdx.x, t = threadIdx.x;
  if (b < 32) {
    int s = b * 256 + t;                 // slot 0..8191
    int kt = s >> 10, c = (s >> 6) & 15, l = s & 63;
    int col = c * 16 + (l & 15);
    int k0 = kt * 32 + (l >> 4) * 8;
    union { uint4 u; unsigned short h[8]; } uu;
#pragma unroll
    for (int j = 0; j < 8; ++j)
      uu.h[j] = f2bf(Wbil[(k0 + j) * ND + col]);
    *(uint4*)(WbT + (size_t)s * 8) = uu.u;
  } else {
    int p = b - 32;
    float s = 0.f;
    for (int k = 0; k < ND; ++k)
      s = fmaf(blr[p * ND + k], Wbil[k * ND + t], s);
    v[p * ND + t] = s;
  }
}

// ---- C_p = W_lr[p]^T @ W_bil  (bf16 MFMA), written in B-frag layout ----
__global__ __launch_bounds__(256) void k_cpre(const float* __restrict__ Wlr,
                                              const unsigned short* __restrict__ WbT,
                                              unsigned short* __restrict__ Cst) {
  __shared__ unsigned short aF[2048 * 8];      // 32 KiB
  int blk = blockIdx.x;
  int p = blk >> 2;
  int i0 = (blk & 3) * 64;
  int tid = threadIdx.x;
  const float* Wp = Wlr + (size_t)p * ND * ND;
#pragma unroll
  for (int it = 0; it < 8; ++it) {
    int s = tid + it * 256;                    // slot = ((kt*4 + r)*64 + l)
    int kt = s >> 8, r = (s >> 6) & 3, l = s & 63;
    int i = r * 16 + (l & 15);
    int k0 = kt * 32 + (l >> 4) * 8;
    union { uint4 u; unsigned short h[8]; } uu;
#pragma unroll
    for (int j = 0; j < 8; ++j)                // A[i][k] = Wlr[p][k][i0+i]
      uu.h[j] = f2bf(Wp[(size_t)(k0 + j) * ND + i0 + i]);
    *(uint4*)(aF + (size_t)s * 8) = uu.u;
  }
  __syncthreads();
  int w = tid >> 6, l = tid & 63;
  f32x4 zero = {0.f, 0.f, 0.f, 0.f};
  f32x4 acc[16];
#pragma unroll
  for (int c = 0; c < 16; ++c) acc[c] = zero;
  for (int kt = 0; kt < 8; ++kt) {
    bf16x8 a = *(const bf16x8*)(aF + (size_t)((kt * 4 + w) * 64 + l) * 8);
#pragma unroll
    for (int c = 0; c < 16; ++c) {
      bf16x8 bb = *(const bf16x8*)(WbT + (size_t)((kt * 16 + c) * 64 + l) * 8);
      acc[c] = __builtin_amdgcn_mfma_f32_16x16x32_bf16(a, bb, acc[c], 0, 0, 0);
    }
  }
  unsigned short* Cp = Cst + (size_t)p * ND * ND;
#pragma unroll
  for (int c = 0; c < 16; ++c) {
#pragma unroll
    for (int q = 0; q < 4; ++q) {
      int i = i0 + w * 16 + ((l >> 4) * 4) + q;
      int j = c * 16 + (l & 15);
      int pos = ((i >> 5) * 16 + (j >> 4)) * 512 + (((i >> 3) & 3) * 16 + (j & 15)) * 8 + (i & 7);
      Cp[pos] = f2bf(acc[c][q]);
    }
  }
}

// ---- main: per 64-row CSR tile: t = z_src@C_p ; score = (t+v_p)·z_dst + b --
// v4: staging loads are per-ROW 1KB contiguous bursts (lane l reads cols
// [4l,4l+4) of one row) — 64x fewer/larger L3 requests than the old per-lane
// 16B gather, which was the R3-R5 ~70us floor. Frag transpose moved to the
// LDS-write side (conflicts hidden under load latency; MFMA reads stay
// contiguous). B read in-loop from L2 (panels are L2-resident).
__global__ __launch_bounds__(256, 2) void k_main(const float* __restrict__ zsrc,
                                                 const float* __restrict__ zdst,
                                                 const int* __restrict__ perm,
                                                 const int* __restrict__ hdr,
                                                 const unsigned short* __restrict__ Cst,
                                                 const float* __restrict__ v,
                                                 const float* __restrict__ bbil,
                                                 float* __restrict__ out) {
  __shared__ unsigned short aF[2048 * 8];      // 32 KiB A-frag tile
  __shared__ unsigned short zL[64 * 256];      // 32 KiB zdst tile (row-major bf16)
  __shared__ int eids[64];
  __shared__ int shdr[18];
  __shared__ float red[4][64];
  int tid = threadIdx.x;
  if (tid < 18) shdr[tid] = hdr[tid];
  __syncthreads();
  int bid = blockIdx.x;
  if (bid >= shdr[9 + NP]) return;
  int p = 0;
  while (p < NP - 1 && bid >= shdr[9 + p + 1]) ++p;
  int t = bid - shdr[9 + p];
  int cnt = shdr[p + 1] - shdr[p];
  int ebase = shdr[p] + t * 64;
  int nrow = cnt - t * 64; if (nrow > 64) nrow = 64;
  if (tid < 64) {
    int r = tid < nrow ? tid : nrow - 1;
    eids[tid] = perm[ebase + r];
  }
  __syncthreads();
  int w = tid >> 6, l = tid & 63;
  // ---- staging: wave w owns rows [w*16, w*16+16); lane l cols [4l, 4l+4) ----
#pragma unroll
  for (int i = 0; i < 16; ++i) {
    int row = w * 16 + i;
    int e = eids[row];
    f32x4 fs = ((const f32x4*)(zsrc + (size_t)e * ND))[l];   // 1KB/instr contiguous
    f32x4 fd = ((const f32x4*)(zdst + (size_t)e * ND))[l];
    union { ushort4 u; unsigned short h[4]; } us, ud;
#pragma unroll
    for (int j = 0; j < 4; ++j) { us.h[j] = f2bf(fs[j]); ud.h[j] = f2bf(fd[j]); }
    // zdst row-major
    *(ushort4*)((char*)zL + row * 512 + l * 8) = ud.u;
    // A-frag: col c=4l+j -> kt=l>>3, lfrag=((l&7)>>1)*16 + i, j=4*(l&1)+j
    int slot = ((l >> 3) * 4 + w) * 64 + ((l & 7) >> 1) * 16 + i;
    *(ushort4*)((char*)aF + slot * 16 + (l & 1) * 8) = us.u;
  }
  __syncthreads();

  const unsigned short* Cp = Cst + (size_t)p * ND * ND;
  f32x4 zero = {0.f, 0.f, 0.f, 0.f};
  f32x4 acc[4][4];
#pragma unroll
  for (int r = 0; r < 4; ++r)
#pragma unroll
    for (int c = 0; c < 4; ++c) acc[r][c] = zero;
#pragma unroll
  for (int kt = 0; kt < 8; ++kt) {
    bf16x8 a[4];
#pragma unroll
    for (int r = 0; r < 4; ++r)
      a[r] = *(const bf16x8*)(aF + (size_t)((kt * 4 + r) * 64 + l) * 8);
#pragma unroll
    for (int cl = 0; cl < 4; ++cl) {
      bf16x8 bb = *(const bf16x8*)(Cp + (size_t)((kt * 16 + w * 4 + cl) * 64 + l) * 8);
#pragma unroll
      for (int r = 0; r < 4; ++r)
        acc[r][cl] = __builtin_amdgcn_mfma_f32_16x16x32_bf16(a[r], bb, acc[r][cl], 0, 0, 0);
    }
  }
  float vloc[4];
#pragma unroll
  for (int cl = 0; cl < 4; ++cl)
    vloc[cl] = v[p * ND + (w * 4 + cl) * 16 + (l & 15)];
#pragma unroll
  for (int r = 0; r < 4; ++r) {
#pragma unroll
    for (int q = 0; q < 4; ++q) {
      int row = r * 16 + ((l >> 4) * 4) + q;   // D-layout: col=l&15, row=(l>>4)*4+reg
      float sv = 0.f;
#pragma unroll
      for (int cl = 0; cl < 4; ++cl) {
        int col = (w * 4 + cl) * 16 + (l & 15);
        unsigned short hz = zL[row * 256 + col];
        float zv = __uint_as_float(((unsigned int)hz) << 16);
        sv = fmaf(acc[r][cl][q] + vloc[cl], zv, sv);
      }
      sv += __shfl_xor(sv, 1, 64);
      sv += __shfl_xor(sv, 2, 64);
      sv += __shfl_xor(sv, 4, 64);
      sv += __shfl_xor(sv, 8, 64);
      if ((l & 15) == 0) red[w][row] = sv;
    }
  }
  __syncthreads();
  if (tid < 64 && tid < nrow) {
    float sc = red[0][tid] + red[1][tid] + red[2][tid] + red[3][tid] + bbil[0];
    out[eids[tid]] = sc;
  }
}

extern "C" void kernel_launch(void* const* d_in, const int* in_sizes, int n_in,
                              void* d_out, int out_size, void* d_ws, size_t ws_size,
                              hipStream_t stream) {
  // setup_inputs() dict order: z_src, z_dst, W_lr, b_lr, W_bil, b_bil, lr_pair_idx
  const float* zsrc = (const float*)d_in[0];
  const float* zdst = (const float*)d_in[1];
  const float* Wlr  = (const float*)d_in[2];
  const float* blr  = (const float*)d_in[3];
  const float* Wbil = (const float*)d_in[4];
  const float* bbil = (const float*)d_in[5];
  const void*  idx  = (const void*)d_in[6];   // int32 or int64 — sniffed per block
  float* out = (float*)d_out;

  char* ws = (char*)d_ws;
  int* hdr    = (int*)ws;                                  // 72 B
  int* counts = (int*)(ws + 4096);                         // 2 KiB
  int* bases  = (int*)(ws + 8192);                         // 2 KiB
  int* perm   = (int*)(ws + 16384);                        // 256 KiB (CSR)
  unsigned short* WbT = (unsigned short*)(ws + 16384 + (size_t)NE * 4);            // 128 KiB
  float* v = (float*)(ws + 16384 + (size_t)NE * 4 + 131072);                       // 8 KiB
  unsigned short* Cst = (unsigned short*)(ws + 16384 + (size_t)NE * 4 + 131072 + 8192); // 1 MiB

  k_prep<<<40, 256, 0, stream>>>(Wbil, blr, WbT, v);
  k_hist<<<RBLK, 256, 0, stream>>>(idx, counts);
  k_scan<<<1, 64, 0, stream>>>(counts, hdr, bases);
  k_scatter<<<RBLK, 256, 0, stream>>>(idx, bases, perm);
  k_cpre<<<32, 256, 0, stream>>>(Wlr, WbT, Cst);
  // max total tiles = sum ceil(cnt_p/64) <= 1024 + 8
  k_main<<<1032, 256, 0, stream>>>(zsrc, zdst, perm, hdr, Cst, v, bbil, out);
}